// Round 1
// baseline (221.447 us; speedup 1.0000x reference)
//
#include <hip/hip_runtime.h>
#include <stdint.h>

// ---------------------------------------------------------------------------
// FastHelgasonLayer: weights are IFFTs of 16-sparse spectra => rank-32 exactly.
//   W_fc  = U_fc(2048x32) @ V_fc(32x8192),  W_proj = U_pr(8192x32) @ V_pr(32x2048)
// Pipeline: build factors -> T1 = x@U_fc (MFMA) -> hT = gelu(Vt*T1^T+b) (MFMA,K=32)
//           -> T2 = h@U_pr (VALU fdot2) -> out = T2@V_pr + b2 (MFMA,K=32)
// ---------------------------------------------------------------------------

typedef short bfrag8 __attribute__((ext_vector_type(8)));   // 8 bf16 (guide-verified frag type)
typedef float f32x4  __attribute__((ext_vector_type(4)));
typedef _Float16 h2_t __attribute__((ext_vector_type(2)));

#define LFFT  8388608u      // 2^23
#define LMASK 8388607u
#define TWO_PI_OVER_L 7.4901405658478575e-7f

__device__ __forceinline__ unsigned short f2bf(float f) {
    unsigned u = __float_as_uint(f);
    u = (u + 0x7FFFu + ((u >> 16) & 1u)) >> 16;   // RTN-even
    return (unsigned short)u;
}
__device__ __forceinline__ unsigned packh2(float a, float b) {
    _Float16 ha = (_Float16)a, hb = (_Float16)b;
    unsigned short ua = __builtin_bit_cast(unsigned short, ha);
    unsigned short ub = __builtin_bit_cast(unsigned short, hb);
    return (unsigned)ua | ((unsigned)ub << 16);
}
__device__ __forceinline__ float geluf(float v) {
    return 0.5f * v * (1.0f + erff(v * 0.70710678118654752f)); // exact erf gelu
}

// --------------------------- factor builders ------------------------------
// U side (carries coeff * scale / L). out layout: [32 r][rows] (B^T rows for MFMA)
__global__ void k_build_ua(const float* __restrict__ cr, const float* __restrict__ ci,
                           const int* __restrict__ idx, const float* __restrict__ scale,
                           unsigned short* __restrict__ out, int rows, int shift) {
    int i = blockIdx.x * 256 + threadIdx.x;
    if (i >= rows) return;
    float sc = scale[0] * (1.0f / (float)LFFT);
    #pragma unroll
    for (int k = 0; k < 16; ++k) {
        int v = idx[k];
        bool keep = true;                        // last-write-wins for duplicate indices
        for (int j = k + 1; j < 16; ++j) keep = keep && (idx[j] != v);
        unsigned s  = (((unsigned)v) << shift) & LMASK;
        unsigned ph = (s * (unsigned)i) & LMASK; // exact mod 2^23 via u32 wrap
        float sn, cs;
        __sincosf((float)ph * TWO_PI_OVER_L, &sn, &cs);
        float a = keep ? cr[k] * sc : 0.0f;
        float b = keep ? ci[k] * sc : 0.0f;
        out[(size_t)(2 * k) * rows + i]     = f2bf(a * cs - b * sn);  // Re
        out[(size_t)(2 * k + 1) * rows + i] = f2bf(a * sn + b * cs);  // Im
    }
}

// U_pr packed as f16 pairs along f: out[kp][r] = half2(U2[2kp][r], U2[2kp+1][r])
__global__ void k_build_u2p(const float* __restrict__ cr, const float* __restrict__ ci,
                            const int* __restrict__ idx, const float* __restrict__ scale,
                            unsigned* __restrict__ out) {
    int kp = blockIdx.x * 256 + threadIdx.x;   // [0, 4096)
    if (kp >= 4096) return;
    float sc = scale[0] * (1.0f / (float)LFFT);
    unsigned f0 = 2u * (unsigned)kp;
    #pragma unroll
    for (int k = 0; k < 16; ++k) {
        int v = idx[k];
        bool keep = true;
        for (int j = k + 1; j < 16; ++j) keep = keep && (idx[j] != v);
        unsigned s   = (((unsigned)v) << 10) & LMASK;   // stride 1024 along f
        unsigned ph0 = (s * f0) & LMASK;
        unsigned ph1 = (ph0 + s) & LMASK;
        float sn0, cs0, sn1, cs1;
        __sincosf((float)ph0 * TWO_PI_OVER_L, &sn0, &cs0);
        __sincosf((float)ph1 * TWO_PI_OVER_L, &sn1, &cs1);
        float a = keep ? cr[k] * sc : 0.0f;
        float b = keep ? ci[k] * sc : 0.0f;
        float Ar0 = a * cs0 - b * sn0, Ai0 = a * sn0 + b * cs0;
        float Ar1 = a * cs1 - b * sn1, Ai1 = a * sn1 + b * cs1;
        out[(size_t)kp * 32 + 2 * k]     = packh2(Ar0, Ar1);
        out[(size_t)kp * 32 + 2 * k + 1] = packh2(Ai0, Ai1);
    }
}

// V side (unit exponentials, interleave rule for re/im columns). out: [nrows][32] bf16
__global__ void k_build_vt(const int* __restrict__ idx,
                           unsigned short* __restrict__ out, int nrows) {
    int j = blockIdx.x * 256 + threadIdx.x;
    if (j >= nrows) return;
    unsigned m = ((unsigned)j) >> 1;
    int p = j & 1;
    #pragma unroll
    for (int k = 0; k < 16; ++k) {
        unsigned s  = ((unsigned)idx[k]) & LMASK;
        unsigned ph = (s * m) & LMASK;
        float sn, cs;
        __sincosf((float)ph * TWO_PI_OVER_L, &sn, &cs);
        float e0 = p ? sn : cs;        // pairs with Re-factor
        float e1 = p ? cs : -sn;       // pairs with Im-factor
        out[(size_t)j * 32 + 2 * k]     = f2bf(e0);
        out[(size_t)j * 32 + 2 * k + 1] = f2bf(e1);
    }
}

// --------------------------- T1 = x @ U_fc (MFMA, K=2048, ksplit 8) --------
__global__ __launch_bounds__(256) void k_gemm_t1(const float* __restrict__ x,
                                                 const unsigned short* __restrict__ ufct,
                                                 float* __restrict__ t1p) {
    __shared__ unsigned short lA[128 * 32];
    __shared__ unsigned short lB[32 * 32];
    int tid = threadIdx.x;
    int ks = blockIdx.x, tb = blockIdx.y;
    int lane = tid & 63, wid = tid >> 6;
    int lr = lane & 15, lk = (lane >> 4) << 3;
    f32x4 acc[2][2];
    #pragma unroll
    for (int mi = 0; mi < 2; ++mi)
        #pragma unroll
        for (int nj = 0; nj < 2; ++nj) { f32x4 z = {0.f, 0.f, 0.f, 0.f}; acc[mi][nj] = z; }
    for (int kst = 0; kst < 8; ++kst) {
        int k0 = ks * 256 + kst * 32;
        __syncthreads();
        #pragma unroll
        for (int e = 0; e < 4; ++e) {                  // stage x tile -> bf16
            int e4 = tid + e * 256;                    // [0,1024)
            int row = e4 >> 3, c4 = (e4 & 7) << 2;
            float4 v = *(const float4*)(x + (size_t)(tb * 128 + row) * 2048 + k0 + c4);
            ushort4 h;
            h.x = f2bf(v.x); h.y = f2bf(v.y); h.z = f2bf(v.z); h.w = f2bf(v.w);
            *(ushort4*)(lA + row * 32 + c4) = h;
        }
        if (tid < 128) {                               // stage U_fct chunk [32 r][32 k]
            int r = tid >> 2, c8 = (tid & 3) << 3;
            *(uint4*)(lB + r * 32 + c8) = *(const uint4*)(ufct + (size_t)r * 2048 + k0 + c8);
        }
        __syncthreads();
        bfrag8 a0 = *(const bfrag8*)(lA + (wid * 32 + lr) * 32 + lk);
        bfrag8 a1 = *(const bfrag8*)(lA + (wid * 32 + 16 + lr) * 32 + lk);
        bfrag8 b0 = *(const bfrag8*)(lB + lr * 32 + lk);
        bfrag8 b1 = *(const bfrag8*)(lB + (16 + lr) * 32 + lk);
        acc[0][0] = __builtin_amdgcn_mfma_f32_16x16x32_bf16(a0, b0, acc[0][0], 0, 0, 0);
        acc[0][1] = __builtin_amdgcn_mfma_f32_16x16x32_bf16(a0, b1, acc[0][1], 0, 0, 0);
        acc[1][0] = __builtin_amdgcn_mfma_f32_16x16x32_bf16(a1, b0, acc[1][0], 0, 0, 0);
        acc[1][1] = __builtin_amdgcn_mfma_f32_16x16x32_bf16(a1, b1, acc[1][1], 0, 0, 0);
    }
    int r4 = (lane >> 4) << 2;
    #pragma unroll
    for (int mi = 0; mi < 2; ++mi)
        #pragma unroll
        for (int nj = 0; nj < 2; ++nj)
            #pragma unroll
            for (int r = 0; r < 4; ++r) {
                int tok = tb * 128 + wid * 32 + mi * 16 + r4 + r;  // C row = token
                int rr  = nj * 16 + lr;                            // C col = r
                t1p[((size_t)ks * 8192 + tok) * 32 + rr] = acc[mi][nj][r];
            }
}

__global__ void k_reduce_t1(const float* __restrict__ t1p, unsigned short* __restrict__ t1) {
    int e = blockIdx.x * 256 + threadIdx.x;   // 262144
    float s = 0.f;
    #pragma unroll
    for (int c = 0; c < 8; ++c) s += t1p[(size_t)c * 262144 + e];
    t1[e] = f2bf(s);
}

// ------------------ rank-32 GEMM (single K=32 MFMA step) -------------------
// C[M][N] = Arows(Mx32) * Brows(Nx32)^T.
// EPI=0: +bias[m-row], gelu, pack f16 pairs along m -> hTp[kp][8192 tokens]
// EPI=1: +bias[n-col] -> f32 out[M][N]
template <int EPI>
__global__ __launch_bounds__(256) void k_rank32(const unsigned short* __restrict__ Arows,
                                                const unsigned short* __restrict__ Brows,
                                                const float* __restrict__ biasv,
                                                unsigned* __restrict__ outp,
                                                float* __restrict__ outf, int N) {
    __shared__ unsigned short lA[128 * 32];
    __shared__ unsigned short lB[128 * 32];
    __shared__ float lbias[128];
    int tid = threadIdx.x;
    int bx = blockIdx.x, by = blockIdx.y;
    {
        const uint4* ga = (const uint4*)(Arows + (size_t)by * 128 * 32);
        const uint4* gb = (const uint4*)(Brows + (size_t)bx * 128 * 32);
        uint4* la4 = (uint4*)lA; uint4* lb4 = (uint4*)lB;
        la4[tid] = ga[tid]; la4[tid + 256] = ga[tid + 256];
        lb4[tid] = gb[tid]; lb4[tid + 256] = gb[tid + 256];
        if (tid < 128) lbias[tid] = (EPI == 0) ? biasv[by * 128 + tid] : biasv[bx * 128 + tid];
    }
    __syncthreads();
    int lane = tid & 63, wid = tid >> 6;
    int wm = wid >> 1, wn = wid & 1;
    int lr = lane & 15, lk = (lane >> 4) << 3;
    bfrag8 a[4], b[4];
    #pragma unroll
    for (int mi = 0; mi < 4; ++mi) a[mi] = *(const bfrag8*)(lA + (wm * 64 + mi * 16 + lr) * 32 + lk);
    #pragma unroll
    for (int nj = 0; nj < 4; ++nj) b[nj] = *(const bfrag8*)(lB + (wn * 64 + nj * 16 + lr) * 32 + lk);
    f32x4 acc[4][4];
    #pragma unroll
    for (int mi = 0; mi < 4; ++mi)
        #pragma unroll
        for (int nj = 0; nj < 4; ++nj) {
            f32x4 z = {0.f, 0.f, 0.f, 0.f};
            acc[mi][nj] = __builtin_amdgcn_mfma_f32_16x16x32_bf16(a[mi], b[nj], z, 0, 0, 0);
        }
    int r4 = (lane >> 4) << 2;   // C/D: col = lane&15, row = 4*(lane>>4)+reg
    #pragma unroll
    for (int mi = 0; mi < 4; ++mi) {
        int me = wm * 64 + mi * 16 + r4;
        #pragma unroll
        for (int nj = 0; nj < 4; ++nj) {
            int nloc = wn * 64 + nj * 16 + lr;
            if (EPI == 0) {
                float g0 = geluf(acc[mi][nj][0] + lbias[me + 0]);
                float g1 = geluf(acc[mi][nj][1] + lbias[me + 1]);
                float g2 = geluf(acc[mi][nj][2] + lbias[me + 2]);
                float g3 = geluf(acc[mi][nj][3] + lbias[me + 3]);
                size_t kp  = (size_t)((by * 128 + me) >> 1);
                size_t col = (size_t)bx * 128 + nloc;
                outp[kp * 8192 + col]       = packh2(g0, g1);
                outp[(kp + 1) * 8192 + col] = packh2(g2, g3);
            } else {
                float bn = lbias[nloc];
                size_t row = (size_t)by * 128 + me;
                size_t col = (size_t)bx * 128 + nloc;
                outf[(row + 0) * (size_t)N + col] = acc[mi][nj][0] + bn;
                outf[(row + 1) * (size_t)N + col] = acc[mi][nj][1] + bn;
                outf[(row + 2) * (size_t)N + col] = acc[mi][nj][2] + bn;
                outf[(row + 3) * (size_t)N + col] = acc[mi][nj][3] + bn;
            }
        }
    }
}

// ---------------- T2 partials: t2p[slot] = sum_f g[f][tok]*U2[f][r] ---------
__global__ __launch_bounds__(128) void k_pv(const unsigned* __restrict__ hTp,
                                            const unsigned* __restrict__ u2p,
                                            float* __restrict__ t2p, int slot_base) {
    __shared__ unsigned lu[128 * 32];   // 128 kp x 32 r (f16 pairs)
    int tid = threadIdx.x;
    int ks = blockIdx.y;
    int slot = slot_base + ks;
    {
        const uint4* src = (const uint4*)(u2p + (size_t)slot * 128 * 32);
        uint4* dst = (uint4*)lu;
        #pragma unroll
        for (int e = 0; e < 8; ++e) dst[tid + e * 128] = src[tid + e * 128];
    }
    __syncthreads();
    int tok0 = blockIdx.x * 512 + tid;
    const unsigned* hbase = hTp + (size_t)ks * 128 * 8192;   // chunk-local rows
    float acc[4][32];
    #pragma unroll
    for (int j = 0; j < 4; ++j)
        #pragma unroll
        for (int r = 0; r < 32; ++r) acc[j][r] = 0.0f;
    unsigned hc[4];
    #pragma unroll
    for (int j = 0; j < 4; ++j) hc[j] = hbase[tok0 + j * 128];
    for (int i = 0; i < 128; ++i) {
        unsigned hn[4] = {0u, 0u, 0u, 0u};
        if (i < 127) {
            #pragma unroll
            for (int j = 0; j < 4; ++j) hn[j] = hbase[(size_t)(i + 1) * 8192 + tok0 + j * 128];
        }
        const uint4* lrow = (const uint4*)(lu + i * 32);
        #pragma unroll
        for (int q = 0; q < 8; ++q) {
            uint4 u = lrow[q];
            #pragma unroll
            for (int j = 0; j < 4; ++j) {
                h2_t hj = __builtin_bit_cast(h2_t, hc[j]);
                acc[j][q * 4 + 0] = __builtin_amdgcn_fdot2(hj, __builtin_bit_cast(h2_t, u.x), acc[j][q * 4 + 0], false);
                acc[j][q * 4 + 1] = __builtin_amdgcn_fdot2(hj, __builtin_bit_cast(h2_t, u.y), acc[j][q * 4 + 1], false);
                acc[j][q * 4 + 2] = __builtin_amdgcn_fdot2(hj, __builtin_bit_cast(h2_t, u.z), acc[j][q * 4 + 2], false);
                acc[j][q * 4 + 3] = __builtin_amdgcn_fdot2(hj, __builtin_bit_cast(h2_t, u.w), acc[j][q * 4 + 3], false);
            }
        }
        #pragma unroll
        for (int j = 0; j < 4; ++j) hc[j] = hn[j];
    }
    float* outb = t2p + (size_t)slot * (8192 * 32);
    #pragma unroll
    for (int j = 0; j < 4; ++j) {
        float4* o = (float4*)(outb + (size_t)(tok0 + j * 128) * 32);
        #pragma unroll
        for (int q = 0; q < 8; ++q) {
            float4 v = make_float4(acc[j][q * 4 + 0], acc[j][q * 4 + 1], acc[j][q * 4 + 2], acc[j][q * 4 + 3]);
            o[q] = v;
        }
    }
}

__global__ void k_reduce_t2(const float* __restrict__ t2p, unsigned short* __restrict__ t2) {
    int e = blockIdx.x * 256 + threadIdx.x;   // 262144
    float s = 0.f;
    #pragma unroll
    for (int c = 0; c < 32; ++c) s += t2p[(size_t)c * 262144 + e];
    t2[e] = f2bf(s);
}

// ---------------------------------------------------------------------------
extern "C" void kernel_launch(void* const* d_in, const int* in_sizes, int n_in,
                              void* d_out, int out_size, void* d_ws, size_t ws_size,
                              hipStream_t stream) {
    (void)in_sizes; (void)n_in; (void)out_size;
    const float* x   = (const float*)d_in[0];
    const float* fcr = (const float*)d_in[1];
    const float* fci = (const float*)d_in[2];
    const float* fcs = (const float*)d_in[3];
    const float* prr = (const float*)d_in[4];
    const float* pri = (const float*)d_in[5];
    const float* prs = (const float*)d_in[6];
    const float* fcb = (const float*)d_in[7];
    const float* prb = (const float*)d_in[8];
    const int* fidx  = (const int*)d_in[9];
    const int* pidx  = (const int*)d_in[10];
    float* out = (float*)d_out;
    char* ws = (char*)d_ws;

    size_t off = 0;
    auto take = [&](size_t bytes) { size_t p = off; off = (off + bytes + 255) & ~(size_t)255; return p; };
    unsigned short* ufct = (unsigned short*)(ws + take((size_t)32 * 2048 * 2));   // U_fc^T [32][2048]
    unsigned short* vtfc = (unsigned short*)(ws + take((size_t)8192 * 32 * 2));   // V_fc^T [8192][32]
    unsigned*       u2p  = (unsigned*)(ws + take((size_t)4096 * 32 * 4));         // U_pr f16-pairs [4096][32]
    unsigned short* vprt = (unsigned short*)(ws + take((size_t)2048 * 32 * 2));   // V_pr^T [2048][32]
    float*          t1p  = (float*)(ws + take((size_t)8 * 8192 * 32 * 4));        // T1 partials
    unsigned short* t1   = (unsigned short*)(ws + take((size_t)8192 * 32 * 2));   // T1 bf16
    float*          t2p  = (float*)(ws + take((size_t)32 * 8192 * 32 * 4));       // T2 partials
    unsigned short* t2   = (unsigned short*)(ws + take((size_t)8192 * 32 * 2));   // T2 bf16
    size_t fixed = off;
    int NC = 1;   // chunk hT by available workspace
    while (NC < 8 && fixed + ((size_t)134217728 / NC) > ws_size) NC <<= 1;
    unsigned* hTp = (unsigned*)(ws + fixed);

    // factor builders
    k_build_ua <<<dim3(8),  256, 0, stream>>>(fcr, fci, fidx, fcs, ufct, 2048, 12);
    k_build_vt <<<dim3(32), 256, 0, stream>>>(fidx, vtfc, 8192);
    k_build_u2p<<<dim3(16), 256, 0, stream>>>(prr, pri, pidx, prs, u2p);
    k_build_vt <<<dim3(8),  256, 0, stream>>>(pidx, vprt, 2048);

    // T1 = x @ U_fc
    k_gemm_t1  <<<dim3(8, 64), 256, 0, stream>>>(x, ufct, t1p);
    k_reduce_t1<<<dim3(1024),  256, 0, stream>>>(t1p, t1);

    // hT = gelu(Vfc^T x T1^T + b1)  (chunked over f), then T2 partials
    int MC = 8192 / NC;
    for (int c = 0; c < NC; ++c) {
        k_rank32<0><<<dim3(64, MC / 128), 256, 0, stream>>>(
            vtfc + (size_t)c * MC * 32, t1, fcb + (size_t)c * MC, hTp, nullptr, 8192);
        k_pv<<<dim3(16, 32 / NC), 128, 0, stream>>>(hTp, u2p, t2p, c * (32 / NC));
    }
    k_reduce_t2<<<dim3(1024), 256, 0, stream>>>(t2p, t2);

    // out = T2 @ V_pr + b2
    k_rank32<1><<<dim3(16, 64), 256, 0, stream>>>(t2, vprt, prb, nullptr, out, 2048);
}

// Round 2
// 80.017 us; speedup vs baseline: 2.7675x; 2.7675x over previous
//
#include <hip/hip_runtime.h>
#include <stdint.h>

// ---------------------------------------------------------------------------
// FastHelgasonLayer, fully fused: weights are IFFTs of 16-sparse spectra
// => exactly rank-32. W_fc = U_fc(2048x32)V_fc(32x8192), W_proj likewise.
// One builder kernel + one fused kernel:
//   per 32-token block: T1 = x@U_fc -> loop f-chunks: S=Vfc*T1^T, gelu,
//   T2 += h@U_pr -> out = T2@V_pr + b2. Only HBM traffic: x in, out out.
// ---------------------------------------------------------------------------

typedef short bfrag8 __attribute__((ext_vector_type(8)));   // 8 bf16
typedef float f32x4  __attribute__((ext_vector_type(4)));

#define LFFT  8388608u      // 2^23
#define LMASK 8388607u
#define TWO_PI_OVER_L 7.4901405658478575e-7f

__device__ __forceinline__ unsigned short f2bf(float f) {
    unsigned u = __float_as_uint(f);
    u = (u + 0x7FFFu + ((u >> 16) & 1u)) >> 16;   // RTN-even
    return (unsigned short)u;
}
__device__ __forceinline__ float gelu_fast(float x) {
    // tanh-form gelu: x * sigmoid(2*0.79788456*(x + 0.044715 x^3)); max err ~3e-3
    float xx = x * x;
    float p  = fmaf(xx, 0.044715f, 1.0f);
    float u2 = x * p * -1.5957691216057308f;      // -2*sqrt(2/pi)
    float e  = __expf(u2);
    return x * __builtin_amdgcn_rcpf(1.0f + e);
}

// --------------------------- factor builder (one kernel) -------------------
__device__ __forceinline__ void vt_body(const int* __restrict__ idx,
                                        unsigned short* __restrict__ out, int j) {
    unsigned m = ((unsigned)j) >> 1;
    int p = j & 1;
    #pragma unroll
    for (int k = 0; k < 16; ++k) {
        unsigned s  = ((unsigned)idx[k]) & LMASK;
        unsigned ph = (s * m) & LMASK;
        float sn, cs;
        __sincosf((float)ph * TWO_PI_OVER_L, &sn, &cs);
        float e0 = p ? sn : cs;        // pairs with Re-factor
        float e1 = p ? cs : -sn;       // pairs with Im-factor
        out[(size_t)j * 32 + 2 * k]     = f2bf(e0);
        out[(size_t)j * 32 + 2 * k + 1] = f2bf(e1);
    }
}

__global__ void k_build(const float* __restrict__ fcr, const float* __restrict__ fci,
                        const int* __restrict__ fidx, const float* __restrict__ fcs,
                        const float* __restrict__ prr, const float* __restrict__ pri,
                        const int* __restrict__ pidx, const float* __restrict__ prs,
                        unsigned short* __restrict__ ufct, unsigned short* __restrict__ vtfc,
                        unsigned short* __restrict__ u2t,  unsigned short* __restrict__ vprt) {
    int b = blockIdx.x, t = threadIdx.x;
    if (b < 8) {                       // U_fc^T [32 r][2048 i], carries coeff*scale/L
        int i = b * 256 + t;
        float sc = fcs[0] * (1.0f / (float)LFFT);
        #pragma unroll
        for (int k = 0; k < 16; ++k) {
            int v = fidx[k];
            bool keep = true;          // last-write-wins for duplicate indices
            for (int j = k + 1; j < 16; ++j) keep = keep && (fidx[j] != v);
            unsigned s  = (((unsigned)v) << 12) & LMASK;
            unsigned ph = (s * (unsigned)i) & LMASK;
            float sn, cs;
            __sincosf((float)ph * TWO_PI_OVER_L, &sn, &cs);
            float a = keep ? fcr[k] * sc : 0.0f;
            float bb = keep ? fci[k] * sc : 0.0f;
            ufct[(size_t)(2 * k) * 2048 + i]     = f2bf(a * cs - bb * sn);
            ufct[(size_t)(2 * k + 1) * 2048 + i] = f2bf(a * sn + bb * cs);
        }
    } else if (b < 40) {               // V_fc^T [8192 f][32 r]
        vt_body(fidx, vtfc, (b - 8) * 256 + t);
    } else if (b < 72) {               // U_pr^T [32 r][8192 f], carries coeff*scale/L
        int f = (b - 40) * 256 + t;
        float sc = prs[0] * (1.0f / (float)LFFT);
        #pragma unroll
        for (int k = 0; k < 16; ++k) {
            int v = pidx[k];
            bool keep = true;
            for (int j = k + 1; j < 16; ++j) keep = keep && (pidx[j] != v);
            unsigned s  = (((unsigned)v) << 10) & LMASK;
            unsigned ph = (s * (unsigned)f) & LMASK;
            float sn, cs;
            __sincosf((float)ph * TWO_PI_OVER_L, &sn, &cs);
            float a = keep ? prr[k] * sc : 0.0f;
            float bb = keep ? pri[k] * sc : 0.0f;
            u2t[(size_t)(2 * k) * 8192 + f]     = f2bf(a * cs - bb * sn);
            u2t[(size_t)(2 * k + 1) * 8192 + f] = f2bf(a * sn + bb * cs);
        }
    } else {                           // V_pr^T [2048 d][32 r]
        vt_body(pidx, vprt, (b - 72) * 256 + t);
    }
}

// --------------------------- fused MLP kernel ------------------------------
__global__ __launch_bounds__(512) void k_fused(
    const float* __restrict__ x,                 // [8192 tok][2048]
    const unsigned short* __restrict__ ufct,     // [32 r][2048 k]
    const unsigned short* __restrict__ vtfc,     // [8192 f][32 r]
    const unsigned short* __restrict__ u2t,      // [32 r][8192 f]
    const unsigned short* __restrict__ vprt,     // [2048 d][32 r]
    const float* __restrict__ fcb,               // [8192]
    const float* __restrict__ prb,               // [2048]
    float* __restrict__ out)                     // [8192 tok][2048]
{
    __shared__ __align__(16) char smem[32768 + 2048];
    float*          red = (float*)smem;                     // [8][1024] (phase A / T2 reduce)
    unsigned short* lT1 = (unsigned short*)(smem + 32768);  // [32 tok][32 r]
    unsigned short* lT2 = lT1;                              // aliased (disjoint lifetime)

    const int tid  = threadIdx.x;
    const int w    = tid >> 6;          // wave 0..7
    const int lane = tid & 63;
    const int lr   = lane & 15;
    const int hi   = lane >> 4;         // 0..3
    const size_t tok0 = (size_t)blockIdx.x * 32;

    // ---------------- Phase A: T1 = x_blk @ U_fc (K=2048, split over waves) --
    f32x4 acc[2][2];
    #pragma unroll
    for (int mi = 0; mi < 2; ++mi)
        #pragma unroll
        for (int nj = 0; nj < 2; ++nj) { f32x4 z = {0.f,0.f,0.f,0.f}; acc[mi][nj] = z; }
    #pragma unroll 1
    for (int step = 0; step < 8; ++step) {
        int k = step * 256 + w * 32 + hi * 8;
        bfrag8 af[2], bf_[2];
        #pragma unroll
        for (int mi = 0; mi < 2; ++mi) {
            const float* xp = x + (tok0 + mi * 16 + lr) * 2048 + k;
            float4 v0 = *(const float4*)xp;
            float4 v1 = *(const float4*)(xp + 4);
            bfrag8 a;
            a[0] = f2bf(v0.x); a[1] = f2bf(v0.y); a[2] = f2bf(v0.z); a[3] = f2bf(v0.w);
            a[4] = f2bf(v1.x); a[5] = f2bf(v1.y); a[6] = f2bf(v1.z); a[7] = f2bf(v1.w);
            af[mi] = a;
        }
        #pragma unroll
        for (int nj = 0; nj < 2; ++nj)
            bf_[nj] = *(const bfrag8*)(ufct + (size_t)(nj * 16 + lr) * 2048 + k);
        #pragma unroll
        for (int mi = 0; mi < 2; ++mi)
            #pragma unroll
            for (int nj = 0; nj < 2; ++nj)
                acc[mi][nj] = __builtin_amdgcn_mfma_f32_16x16x32_bf16(af[mi], bf_[nj], acc[mi][nj], 0, 0, 0);
    }
    #pragma unroll
    for (int mi = 0; mi < 2; ++mi)
        #pragma unroll
        for (int nj = 0; nj < 2; ++nj)
            #pragma unroll
            for (int r = 0; r < 4; ++r)
                red[w * 1024 + (mi * 16 + hi * 4 + r) * 32 + nj * 16 + lr] = acc[mi][nj][r];
    __syncthreads();
    for (int e = tid; e < 1024; e += 512) {
        float s = 0.f;
        #pragma unroll
        for (int w2 = 0; w2 < 8; ++w2) s += red[w2 * 1024 + e];
        lT1[e] = f2bf(s);
    }
    __syncthreads();
    bfrag8 t1b[2];   // T1 as B-operand (N=tok, K=r) — loop-invariant, hoisted
    #pragma unroll
    for (int nj = 0; nj < 2; ++nj)
        t1b[nj] = *(const bfrag8*)(lT1 + (nj * 16 + lr) * 32 + hi * 8);

    // ---------------- Phase B: f-loop (32 chunks of 256 f) ------------------
    f32x4 t2acc[2][2];
    #pragma unroll
    for (int mi = 0; mi < 2; ++mi)
        #pragma unroll
        for (int nj = 0; nj < 2; ++nj) { f32x4 z = {0.f,0.f,0.f,0.f}; t2acc[mi][nj] = z; }

    auto load_frags = [&](int itn, bfrag8& A0, bfrag8& A1, bfrag8& B0, bfrag8& B1,
                          float4& C0, float4& C1) {
        int fb = itn * 256 + w * 32;
        A0 = *(const bfrag8*)(vtfc + (size_t)(fb + lr) * 32 + hi * 8);
        A1 = *(const bfrag8*)(vtfc + (size_t)(fb + 16 + lr) * 32 + hi * 8);
        B0 = *(const bfrag8*)(u2t + (size_t)lr * 8192 + fb + hi * 8);
        B1 = *(const bfrag8*)(u2t + (size_t)(16 + lr) * 8192 + fb + hi * 8);
        C0 = *(const float4*)(fcb + fb + hi * 4);
        C1 = *(const float4*)(fcb + fb + 16 + hi * 4);
    };
    auto store_s = [&](const f32x4& s, const float4& vb, int mi, int nj) {
        float g0 = gelu_fast(s[0] + vb.x);
        float g1 = gelu_fast(s[1] + vb.y);
        float g2 = gelu_fast(s[2] + vb.z);
        float g3 = gelu_fast(s[3] + vb.w);
        unsigned p0 = (unsigned)f2bf(g0) | ((unsigned)f2bf(g1) << 16);
        unsigned p1 = (unsigned)f2bf(g2) | ((unsigned)f2bf(g3) << 16);
        int tok  = nj * 16 + lr;
        int f0   = w * 32 + mi * 16 + hi * 4;
        int byte = tok * 512 + ((f0 * 2) ^ ((tok & 7) << 4));   // XOR-swizzled lH
        *(uint2*)(smem + byte) = make_uint2(p0, p1);
    };

    bfrag8 va0, va1, bu0, bu1; float4 vb0, vb1;
    load_frags(0, va0, va1, bu0, bu1, vb0, vb1);
    #pragma unroll 1
    for (int it = 0; it < 32; ++it) {
        // S = Vfc_chunk(Mf x 32) @ T1^T(32 x tok): C row=f, col=tok
        f32x4 z = {0.f,0.f,0.f,0.f};
        f32x4 s00 = __builtin_amdgcn_mfma_f32_16x16x32_bf16(va0, t1b[0], z, 0, 0, 0);
        f32x4 s01 = __builtin_amdgcn_mfma_f32_16x16x32_bf16(va0, t1b[1], z, 0, 0, 0);
        f32x4 s10 = __builtin_amdgcn_mfma_f32_16x16x32_bf16(va1, t1b[0], z, 0, 0, 0);
        f32x4 s11 = __builtin_amdgcn_mfma_f32_16x16x32_bf16(va1, t1b[1], z, 0, 0, 0);
        // prefetch next chunk's fragments (global, L2-resident)
        int itn = (it + 1) & 31;
        bfrag8 na0, na1, nb0, nb1; float4 nc0, nc1;
        load_frags(itn, na0, na1, nb0, nb1, nc0, nc1);
        __syncthreads();                       // prev iter's lH reads complete
        store_s(s00, vb0, 0, 0); store_s(s01, vb0, 0, 1);
        store_s(s10, vb1, 1, 0); store_s(s11, vb1, 1, 1);
        __syncthreads();                       // lH chunk ready
        // T2 += h(tok x f) @ U_pr(f x r); wave w owns k-slice w*32..+32
        #pragma unroll
        for (int mi = 0; mi < 2; ++mi) {
            int tok  = mi * 16 + lr;
            int byte = tok * 512 + (((w * 32 + hi * 8) * 2) ^ ((tok & 7) << 4));
            bfrag8 ha = *(const bfrag8*)(smem + byte);
            t2acc[mi][0] = __builtin_amdgcn_mfma_f32_16x16x32_bf16(ha, bu0, t2acc[mi][0], 0, 0, 0);
            t2acc[mi][1] = __builtin_amdgcn_mfma_f32_16x16x32_bf16(ha, bu1, t2acc[mi][1], 0, 0, 0);
        }
        va0 = na0; va1 = na1; bu0 = nb0; bu1 = nb1; vb0 = nc0; vb1 = nc1;
    }

    // ---------------- T2 cross-wave reduce ----------------------------------
    __syncthreads();                           // last lH reads done before red reuse
    #pragma unroll
    for (int mi = 0; mi < 2; ++mi)
        #pragma unroll
        for (int nj = 0; nj < 2; ++nj)
            #pragma unroll
            for (int r = 0; r < 4; ++r)
                red[w * 1024 + (mi * 16 + hi * 4 + r) * 32 + nj * 16 + lr] = t2acc[mi][nj][r];
    __syncthreads();
    for (int e = tid; e < 1024; e += 512) {
        float s = 0.f;
        #pragma unroll
        for (int w2 = 0; w2 < 8; ++w2) s += red[w2 * 1024 + e];
        lT2[e] = f2bf(s);
    }
    __syncthreads();

    // ---------------- Stage 5: out = T2 @ V_pr^T + b2 -----------------------
    bfrag8 t2a[2];
    #pragma unroll
    for (int mi = 0; mi < 2; ++mi)
        t2a[mi] = *(const bfrag8*)(lT2 + (mi * 16 + lr) * 32 + hi * 8);
    #pragma unroll 1
    for (int nj = 0; nj < 16; ++nj) {
        int d = w * 256 + nj * 16 + lr;
        bfrag8 vp = *(const bfrag8*)(vprt + (size_t)d * 32 + hi * 8);
        float bn = prb[d];
        #pragma unroll
        for (int mi = 0; mi < 2; ++mi) {
            f32x4 z = {0.f,0.f,0.f,0.f};
            f32x4 o = __builtin_amdgcn_mfma_f32_16x16x32_bf16(t2a[mi], vp, z, 0, 0, 0);
            #pragma unroll
            for (int r = 0; r < 4; ++r)
                out[(tok0 + mi * 16 + hi * 4 + r) * 2048 + d] = o[r] + bn;
        }
    }
}

// ---------------------------------------------------------------------------
extern "C" void kernel_launch(void* const* d_in, const int* in_sizes, int n_in,
                              void* d_out, int out_size, void* d_ws, size_t ws_size,
                              hipStream_t stream) {
    (void)in_sizes; (void)n_in; (void)out_size; (void)ws_size;
    const float* x   = (const float*)d_in[0];
    const float* fcr = (const float*)d_in[1];
    const float* fci = (const float*)d_in[2];
    const float* fcs = (const float*)d_in[3];
    const float* prr = (const float*)d_in[4];
    const float* pri = (const float*)d_in[5];
    const float* prs = (const float*)d_in[6];
    const float* fcb = (const float*)d_in[7];
    const float* prb = (const float*)d_in[8];
    const int* fidx  = (const int*)d_in[9];
    const int* pidx  = (const int*)d_in[10];
    float* out = (float*)d_out;
    char* ws = (char*)d_ws;

    size_t off = 0;
    auto take = [&](size_t bytes) { size_t p = off; off = (off + bytes + 255) & ~(size_t)255; return p; };
    unsigned short* ufct = (unsigned short*)(ws + take((size_t)32 * 2048 * 2));   // U_fc^T  [32][2048]
    unsigned short* vtfc = (unsigned short*)(ws + take((size_t)8192 * 32 * 2));   // V_fc^T  [8192][32]
    unsigned short* u2t  = (unsigned short*)(ws + take((size_t)32 * 8192 * 2));   // U_pr^T  [32][8192]
    unsigned short* vprt = (unsigned short*)(ws + take((size_t)2048 * 32 * 2));   // V_pr^T  [2048][32]

    k_build<<<dim3(80), 256, 0, stream>>>(fcr, fci, fidx, fcs, prr, pri, pidx, prs,
                                          ufct, vtfc, u2t, vprt);
    k_fused<<<dim3(256), 512, 0, stream>>>(x, ufct, vtfc, u2t, vprt, fcb, prb, out);
}